// Round 6
// baseline (467.220 us; speedup 1.0000x reference)
//
#include <hip/hip_runtime.h>
#include <hip/hip_bf16.h>
#include <stdint.h>

// Problem dims (fixed): x [1,128,128,1024], E=1024, NH=16, D=64, M=16384.

typedef __attribute__((ext_vector_type(4))) float floatx4;
typedef __attribute__((ext_vector_type(8))) short shortx8;

static __device__ __forceinline__ unsigned short f2bf(float f) {
  unsigned int u = __float_as_uint(f);
  u += 0x7fffu + ((u >> 16) & 1u);  // RNE
  return (unsigned short)(u >> 16);
}

static __device__ __forceinline__ void gload16(const void* g, void* l) {
  __builtin_amdgcn_global_load_lds(
      (const __attribute__((address_space(1))) void*)g,
      (__attribute__((address_space(3))) void*)l, 16, 0, 0);
}

// ---------------- merged f32 -> bf16 convert (unchanged) ----------------
__global__ __launch_bounds__(256) void cvt_all(
    const float* __restrict__ x, const float* __restrict__ Wq,
    const float* __restrict__ Wk, const float* __restrict__ Wv,
    const float* __restrict__ Wo, unsigned short* __restrict__ xb,
    unsigned short* __restrict__ wqkvb, unsigned short* __restrict__ wob) {
  const int b = blockIdx.x;
  const float* src;
  unsigned short* dst;
  int off;
  if (b < 16384) {
    src = x; dst = xb; off = b;
  } else if (b < 17408) {
    src = Wq; dst = wqkvb; off = b - 16384;
  } else if (b < 18432) {
    src = Wk; dst = wqkvb + 1048576; off = b - 17408;
  } else if (b < 19456) {
    src = Wv; dst = wqkvb + 2097152; off = b - 18432;
  } else {
    src = Wo; dst = wob; off = b - 19456;
  }
  const int i = (off * 256 + threadIdx.x) * 4;
  float4 f = *(const float4*)(src + i);
  ushort4 o;
  o.x = f2bf(f.x); o.y = f2bf(f.y); o.z = f2bf(f.z); o.w = f2bf(f.w);
  *(ushort4*)(dst + i) = o;
}

// ------------- 256x256-tile register-pipelined bf16 GEMM: C = A @ BT^T ----
// R6 structural change (R2/R5 both stuck at MfmaUtil 35%): the old
// [reads -> barrier -> lgkm0 -> MFMA -> barrier] lockstep serialized the
// LDS-read pipe (~2300 cyc/K-tile) against the MFMA pipe (~2060 cyc).
// New: ONE barrier per phase; each phase ISSUES the NEXT phase's ds_reads
// before its own MFMA; compiler emits counted lgkmcnt so read-drain hides
// under MFMA. B_h0 is read once/tile and kept in regs for ph0+ph3.
//
// Slot rotation (A slots fixed, B slots swap per tile parity):
//   even tile kt: BA=bX holds B_h0(kt), BB=bY; odd: BA=bY, BB=bX.
//   ph0: MFMA(0,0) aE,BA;  read BB <- B_h1(kt)
//   ph1: MFMA(0,1) aE,BB;  read aO <- A_h1(kt);  stage A0,B0(kt+2); VMCNT
//   ph2: MFMA(1,1) aO,BB;  read aE <- A_h0(kt+1);  stage B1(kt+2)
//   ph3: MFMA(1,0) aO,BA;  read BB <- B_h0(kt+1);  stage A1(kt+2)
// WAR (region staged >= 1 barrier after all reads of it complete):
//   A_h0: read-issued kt-1 ph2, consumed kt ph0 -> safe after kt ph0 bar.
//   B_h0: read-issued kt-1 ph3, consumed kt ph0 -> safe after kt ph0 bar.
//   B_h1: read-issued kt ph0, consumed kt ph1  -> safe after kt ph1 bar.
//   A_h1: read-issued kt ph1, consumed kt ph2  -> safe after kt ph2 bar.
// vmcnt ledger: stages/tile = 8 (ph1:4, ph2:2, ph3:2). At kt ph1 after
//   issuing 4: in flight = tile(kt+1) x8 + 4 -> VMCNT(4) drains tile kt+1
//   before kt ph2/ph3 read it (barrier end-ph1 gives chip-wide guarantee).
//   Prologue: tile0 x8 -> VMCNT(0) hard boundary -> tile1 x8 in flight.
//   Tail: kt>=14 no stages; VMCNT(0) at kt=14 drains tile 15.
//
// MODE 0: N=3072 (q|k|v), bias b0/b1/b2, ReLU on q,k; bf16 out.
// MODE 1: N=1024, bias b0, f32 out.
#define BARRIER()                           \
  do {                                      \
    asm volatile("" ::: "memory");          \
    __builtin_amdgcn_s_barrier();           \
    asm volatile("" ::: "memory");          \
  } while (0)
#define VMCNT(N) asm volatile("s_waitcnt vmcnt(" #N ")" ::: "memory")

template <int MODE>
__global__ __launch_bounds__(512, 2) void gemm256(
    const unsigned short* __restrict__ A,
    const unsigned short* __restrict__ BT,
    const float* __restrict__ b0, const float* __restrict__ b1,
    const float* __restrict__ b2,
    unsigned short* __restrict__ Oq, unsigned short* __restrict__ Ok,
    unsigned short* __restrict__ Ov, float* __restrict__ Of) {
  // 2 buffers x 4 regions (A-H0,A-H1,B-H0,B-H1) x 128rows x 64cols bf16.
  __shared__ __align__(16) unsigned short smem[65536];
  const int t = threadIdx.x;
  const int lane = t & 63, wid = t >> 6;
  const int wm = wid >> 2, wn = wid & 3;     // 2x4 wave grid, 128x64 out/wave
  const int mrow = lane & 15, quad = lane >> 4;

  int bid = blockIdx.x, bm, bn;
  if (MODE == 0) {  // 768 wgs: bijective XCD swizzle, A-panel-major chunks
    int s = (bid & 7) * 96 + (bid >> 3);
    bm = s / 12; bn = s - bm * 12;
  } else {          // 256 wgs
    int s = (bid & 7) * 32 + (bid >> 3);
    bm = s >> 2; bn = s & 3;
  }
  const int m0 = bm << 8;
  const int n0 = bn << 8;

  // Frag-read swizzle: chunkpos = wanted ^ (row&7); row&7 == mrow&7 since
  // all other row offsets are multiples of 8 (16,32,64,128-row strides).
  const int sw0 = ((quad ^ (mrow & 7)) << 3);
  const int sw1 = (((quad ^ 4) ^ (mrow & 7)) << 3);
  const int a_base = wm * 8192 + mrow * 64;
  const int b_base = 16384 + (wn >> 1) * 8192 + (((wn & 1) << 6) + mrow) * 64;
  // Staging: lane writes LDS chunkpos = lane&7 at region-row
  // srow = wid*8+(lane>>3); source col-chunk = chunkpos ^ (srow&7).
  const int s_dst0 = wid * 512 + lane * 8;
  const int srow = wid * 8 + (lane >> 3);
  const int csrc = ((lane & 7) ^ (lane >> 3)) << 3;
  const unsigned short* gAbase = A + (size_t)(m0 + srow) * 1024 + csrc;
  const unsigned short* gBbase = BT + (size_t)(n0 + srow) * 1024 + csrc;

#define STAGE_A(KT, H)                                              \
  do {                                                              \
    const unsigned short* _g = gAbase + ((H) << 17) + ((KT) << 6);  \
    const int _d = (((KT) & 1) << 15) + ((H) << 13) + s_dst0;       \
    gload16(_g, &smem[_d]);                                         \
    gload16(_g + 65536, &smem[_d + 4096]);                          \
  } while (0)
#define STAGE_B(KT, H)                                                     \
  do {                                                                     \
    const unsigned short* _g = gBbase + ((H) << 17) + ((KT) << 6);         \
    const int _d = (((KT) & 1) << 15) + 16384 + ((H) << 13) + s_dst0;      \
    gload16(_g, &smem[_d]);                                                \
    gload16(_g + 65536, &smem[_d + 4096]);                                 \
  } while (0)
#define RD_A(DST, CB, H)                                           \
  do {                                                             \
    const int _ab = (CB) + a_base + ((H) << 12);                   \
    _Pragma("unroll") for (int i = 0; i < 4; ++i) {                \
      DST[i][0] = *(const shortx8*)&smem[_ab + i * 1024 + sw0];    \
      DST[i][1] = *(const shortx8*)&smem[_ab + i * 1024 + sw1];    \
    }                                                              \
  } while (0)
#define RD_B(DST, CB, H)                                           \
  do {                                                             \
    const int _bb = (CB) + b_base + ((H) << 11);                   \
    _Pragma("unroll") for (int j = 0; j < 2; ++j) {                \
      DST[j][0] = *(const shortx8*)&smem[_bb + j * 1024 + sw0];    \
      DST[j][1] = *(const shortx8*)&smem[_bb + j * 1024 + sw1];    \
    }                                                              \
  } while (0)
#define MFMAQ(MH, NH, AS, BS)                                              \
  do {                                                                     \
    _Pragma("unroll") for (int ks = 0; ks < 2; ++ks)                       \
    _Pragma("unroll") for (int i = 0; i < 4; ++i)                          \
    _Pragma("unroll") for (int j = 0; j < 2; ++j)                          \
      acc[(MH) * 4 + i][(NH) * 2 + j] =                                    \
          __builtin_amdgcn_mfma_f32_16x16x32_bf16(                         \
              AS[i][ks], BS[j][ks], acc[(MH) * 4 + i][(NH) * 2 + j], 0, 0, \
              0);                                                          \
  } while (0)

#define KTILE(KT, BA, BB)                                          \
  do {                                                             \
    const int cb = ((KT) & 1) << 15;                               \
    const int cbn = cb ^ 32768;                                    \
    const bool pf = (KT) < 14;                                     \
    const bool rd1 = (KT) < 15;                                    \
    /* ---- ph0: MFMA(0,0); issue B_h1(kt) reads */                \
    RD_B(BB, cb, 1);                                               \
    __builtin_amdgcn_s_setprio(1);                                 \
    MFMAQ(0, 0, aE, BA);                                           \
    __builtin_amdgcn_s_setprio(0);                                 \
    BARRIER();                                                     \
    /* ---- ph1: MFMA(0,1); issue A_h1(kt); stage A0,B0(kt+2) */   \
    RD_A(aO, cb, 1);                                               \
    if (pf) {                                                      \
      STAGE_A((KT) + 2, 0);                                        \
      STAGE_B((KT) + 2, 0);                                        \
      VMCNT(4);                                                    \
    } else {                                                       \
      VMCNT(0);                                                    \
    }                                                              \
    __builtin_amdgcn_s_setprio(1);                                 \
    MFMAQ(0, 1, aE, BB);                                           \
    __builtin_amdgcn_s_setprio(0);                                 \
    BARRIER();                                                     \
    /* ---- ph2: MFMA(1,1); issue A_h0(kt+1); stage B1(kt+2) */    \
    if (rd1) RD_A(aE, cbn, 0);                                     \
    if (pf) STAGE_B((KT) + 2, 1);                                  \
    __builtin_amdgcn_s_setprio(1);                                 \
    MFMAQ(1, 1, aO, BB);                                           \
    __builtin_amdgcn_s_setprio(0);                                 \
    BARRIER();                                                     \
    /* ---- ph3: MFMA(1,0); issue B_h0(kt+1); stage A1(kt+2) */    \
    if (rd1) RD_B(BB, cbn, 0);                                     \
    if (pf) STAGE_A((KT) + 2, 1);                                  \
    __builtin_amdgcn_s_setprio(1);                                 \
    MFMAQ(1, 0, aO, BA);                                           \
    __builtin_amdgcn_s_setprio(0);                                 \
    BARRIER();                                                     \
  } while (0)

  floatx4 acc[8][4] = {};
  shortx8 aE[4][2], aO[4][2], bX[2][2], bY[2][2];

  // Prologue: tile 0 (8 gloads) -> HARD drain -> tile 1 (8 gloads) ->
  // barrier (chip-wide tile-0 resident) -> preload ph0 operands.
  STAGE_A(0, 0); STAGE_A(0, 1); STAGE_B(0, 0); STAGE_B(0, 1);
  __builtin_amdgcn_sched_barrier(0);
  VMCNT(0);
  __builtin_amdgcn_sched_barrier(0);
  STAGE_A(1, 0); STAGE_A(1, 1); STAGE_B(1, 0); STAGE_B(1, 1);
  BARRIER();
  RD_A(aE, 0, 0);  // A_h0(0)
  RD_B(bX, 0, 0);  // B_h0(0)

  for (int kt = 0; kt < 16; kt += 2) {
    KTILE(kt, bX, bY);      // even: BA=bX, BB=bY
    KTILE(kt + 1, bY, bX);  // odd:  BA=bY, BB=bX
  }

  // ---------------- epilogue ----------------
  if (MODE == 0) {
    const int sel = n0 >> 10;
    const float* bb = (sel == 0) ? b0 : ((sel == 1) ? b1 : b2);
    unsigned short* O = (sel == 0) ? Oq : ((sel == 1) ? Ok : Ov);
    const int nb = n0 & 1023;
    float bias[4];
#pragma unroll
    for (int j = 0; j < 4; ++j) bias[j] = bb[nb + wn * 64 + j * 16 + mrow];
    unsigned short* we = &smem[wid * 8192];  // per-wave 128x64 bf16, swizzled
#pragma unroll
    for (int mr = 0; mr < 8; ++mr)
#pragma unroll
      for (int j = 0; j < 4; ++j)
#pragma unroll
        for (int r = 0; r < 4; ++r) {
          const int row = mr * 16 + quad * 4 + r;
          const int col = j * 16 + mrow;
          float v = acc[mr][j][r] + bias[j];
          if (sel < 2) v = fmaxf(v, 0.0f);
          we[row * 64 + (((col >> 3) ^ (row & 7)) << 3) + (col & 7)] = f2bf(v);
        }
    __syncthreads();
#pragma unroll
    for (int it = 0; it < 16; ++it) {
      const int rr = it * 8 + (lane >> 3);
      const int cl = lane & 7;
      uint4 v = *(const uint4*)&we[rr * 64 + ((cl ^ (rr & 7)) << 3)];
      *(uint4*)&O[(size_t)(m0 + wm * 128 + rr) * 1024 + nb + wn * 64 + cl * 8] =
          v;
    }
  } else {
    float* wef = (float*)&smem[wid * 8192];  // per-wave 64x64 f32, swizzled
    float bias[4];
#pragma unroll
    for (int j = 0; j < 4; ++j) bias[j] = b0[n0 + wn * 64 + j * 16 + mrow];
#pragma unroll
    for (int h = 0; h < 2; ++h) {
#pragma unroll
      for (int i = 0; i < 4; ++i)
#pragma unroll
        for (int j = 0; j < 4; ++j)
#pragma unroll
          for (int r = 0; r < 4; ++r) {
            const int row = i * 16 + quad * 4 + r;
            const int col = j * 16 + mrow;
            wef[row * 64 + (((col >> 2) ^ (row & 7)) << 2) + (col & 3)] =
                acc[h * 4 + i][j][r] + bias[j];
          }
      __syncthreads();
#pragma unroll
      for (int it = 0; it < 16; ++it) {
        const int rr = it * 4 + (lane >> 4);
        const int cl = lane & 15;
        float4 v = *(const float4*)&wef[rr * 64 + ((cl ^ (rr & 7)) << 2)];
        *(float4*)&Of[(size_t)(m0 + wm * 128 + h * 64 + rr) * 1024 + n0 +
                      wn * 64 + cl * 4] = v;
      }
      __syncthreads();
    }
  }
#undef KTILE
#undef STAGE_A
#undef STAGE_B
#undef RD_A
#undef RD_B
#undef MFMAQ
}

// ---------------- fused retention (one axis, unchanged) ----------------
__global__ __launch_bounds__(256) void retention_fused(
    const unsigned short* __restrict__ S, const unsigned short* __restrict__ Kb,
    const unsigned short* __restrict__ Vb, unsigned short* __restrict__ D,
    int axis) {
  const int outer = blockIdx.x;
  const int n = blockIdx.y;
  __shared__ unsigned short lS[128 * 72];
  __shared__ unsigned short lKT[64 * 136];
  __shared__ unsigned short lVT[64 * 136];
  unsigned short* lKV = lVT;  // reused for kv^T [e][d] stride 72 after stage 1
  const int t = threadIdx.x;
  const size_t base = (axis == 0) ? ((size_t)outer << 17) : ((size_t)outer << 10);
  const size_t istr = (axis == 0) ? (size_t)1024 : (size_t)131072;
  const size_t nof = (size_t)(n << 6);

#pragma unroll
  for (int it = 0; it < 4; ++it) {
    const int r = it * 32 + (t >> 3);
    const int c = (t & 7) * 8;
    uint4 v = *(const uint4*)&S[base + (size_t)r * istr + nof + c];
    *(uint4*)&lS[r * 72 + c] = v;
  }
#pragma unroll
  for (int it = 0; it < 4; ++it) {
    const int w = it * 32 + (t & 31);
    const int d0 = (t >> 5) * 8;
    const size_t g = base + (size_t)w * istr + nof + d0;
    uint4 k4 = *(const uint4*)&Kb[g];
    uint4 v4 = *(const uint4*)&Vb[g];
    const unsigned short* kp = (const unsigned short*)&k4;
    const unsigned short* vp = (const unsigned short*)&v4;
#pragma unroll
    for (int i = 0; i < 8; ++i) {
      lKT[(d0 + i) * 136 + w] = kp[i];
      lVT[(d0 + i) * 136 + w] = vp[i];
    }
  }
  __syncthreads();

  const int lane = t & 63;
  const int wv = t >> 6;
  const int mrow = lane & 15;
  const int quad = lane >> 4;

  floatx4 acc1[4] = {};
#pragma unroll
  for (int ks = 0; ks < 4; ++ks) {
    shortx8 a = *(const shortx8*)&lVT[(wv * 16 + mrow) * 136 + ks * 32 + quad * 8];
#pragma unroll
    for (int j = 0; j < 4; ++j) {
      shortx8 b = *(const shortx8*)&lKT[(j * 16 + mrow) * 136 + ks * 32 + quad * 8];
      acc1[j] = __builtin_amdgcn_mfma_f32_16x16x32_bf16(a, b, acc1[j], 0, 0, 0);
    }
  }
  __syncthreads();  // all stage-1 reads of lVT done before aliasing as lKV
#pragma unroll
  for (int j = 0; j < 4; ++j)
#pragma unroll
    for (int r = 0; r < 4; ++r)
      lKV[(wv * 16 + quad * 4 + r) * 72 + j * 16 + mrow] = f2bf(acc1[j][r]);
  __syncthreads();

  floatx4 acc2[2][4] = {};
#pragma unroll
  for (int ks = 0; ks < 2; ++ks) {
    shortx8 a2[2], b2[4];
#pragma unroll
    for (int i = 0; i < 2; ++i)
      a2[i] = *(const shortx8*)&lS[(wv * 32 + i * 16 + mrow) * 72 + ks * 32 + quad * 8];
#pragma unroll
    for (int j = 0; j < 4; ++j)
      b2[j] = *(const shortx8*)&lKV[(j * 16 + mrow) * 72 + ks * 32 + quad * 8];
#pragma unroll
    for (int i = 0; i < 2; ++i)
#pragma unroll
      for (int j = 0; j < 4; ++j)
        acc2[i][j] = __builtin_amdgcn_mfma_f32_16x16x32_bf16(a2[i], b2[j],
                                                             acc2[i][j], 0, 0, 0);
  }
  __syncthreads();  // all stage-2 reads of lS done
#pragma unroll
  for (int i = 0; i < 2; ++i)
#pragma unroll
    for (int j = 0; j < 4; ++j)
#pragma unroll
      for (int r = 0; r < 4; ++r) {
        const int row = wv * 32 + i * 16 + quad * 4 + r;
        const int col = j * 16 + mrow;
        lS[row * 72 + col] = f2bf(acc2[i][j][r]);
      }
  __syncthreads();
#pragma unroll
  for (int it = 0; it < 4; ++it) {
    const int row = it * 32 + (t >> 3);
    const int c = (t & 7) * 8;
    uint4 v = *(const uint4*)&lS[row * 72 + c];
    *(uint4*)&D[base + (size_t)row * istr + nof + c] = v;
  }
}

extern "C" void kernel_launch(void* const* d_in, const int* in_sizes, int n_in,
                              void* d_out, int out_size, void* d_ws, size_t ws_size,
                              hipStream_t stream) {
  const float* x  = (const float*)d_in[0];
  const float* Wq = (const float*)d_in[1];
  const float* bq = (const float*)d_in[2];
  const float* Wk = (const float*)d_in[3];
  const float* bk = (const float*)d_in[4];
  const float* Wv = (const float*)d_in[5];
  const float* bv = (const float*)d_in[6];
  const float* Wo = (const float*)d_in[7];
  const float* bo = (const float*)d_in[8];
  float* out = (float*)d_out;

  char* ws = (char*)d_ws;
  unsigned short* xb    = (unsigned short*)(ws + 0);          // 16M elem
  unsigned short* wqkvb = (unsigned short*)(ws + 33554432);   // 3M elem
  unsigned short* wob   = (unsigned short*)(ws + 39845888);   // 1M elem
  unsigned short* qb    = (unsigned short*)(ws + 41943040);   // 16M elem
  unsigned short* kb    = (unsigned short*)(ws + 75497472);   // 16M elem
  unsigned short* vb    = (unsigned short*)(ws + 109051904);  // 16M elem
  unsigned short* out1  = xb;  // reuse: x not needed after projections
  unsigned short* out2  = qb;  // reuse: q not needed after axis-0 retention

  cvt_all<<<dim3(20480), dim3(256), 0, stream>>>(x, Wq, Wk, Wv, Wo, xb, wqkvb, wob);
  gemm256<0><<<dim3(768), dim3(512), 0, stream>>>(
      xb, wqkvb, bq, bk, bv, qb, kb, vb, (float*)nullptr);
  retention_fused<<<dim3(128, 16), dim3(256), 0, stream>>>(qb, kb, vb, out1, 0);
  retention_fused<<<dim3(128, 16), dim3(256), 0, stream>>>(out1, kb, vb, out2, 1);
  gemm256<1><<<dim3(256), dim3(512), 0, stream>>>(
      out2, wob, bo, nullptr, nullptr, nullptr, nullptr, nullptr, out);
}

// Round 8
// 323.415 us; speedup vs baseline: 1.4446x; 1.4446x over previous
//
#include <hip/hip_runtime.h>
#include <hip/hip_bf16.h>
#include <stdint.h>

// Problem dims (fixed): x [1,128,128,1024], E=1024, NH=16, D=64, M=16384.
// R8 = R7 resubmitted verbatim (R7 hit an infra container failure; audit
// found no kernel-side hang/fault mechanism -- same ledger as passing R5).

typedef __attribute__((ext_vector_type(4))) float floatx4;
typedef __attribute__((ext_vector_type(8))) short shortx8;

static __device__ __forceinline__ unsigned short f2bf(float f) {
  unsigned int u = __float_as_uint(f);
  u += 0x7fffu + ((u >> 16) & 1u);  // RNE
  return (unsigned short)(u >> 16);
}

static __device__ __forceinline__ void gload16(const void* g, void* l) {
  __builtin_amdgcn_global_load_lds(
      (const __attribute__((address_space(1))) void*)g,
      (__attribute__((address_space(3))) void*)l, 16, 0, 0);
}

// ---------------- merged f32 -> bf16 convert (unchanged) ----------------
__global__ __launch_bounds__(256) void cvt_all(
    const float* __restrict__ x, const float* __restrict__ Wq,
    const float* __restrict__ Wk, const float* __restrict__ Wv,
    const float* __restrict__ Wo, unsigned short* __restrict__ xb,
    unsigned short* __restrict__ wqkvb, unsigned short* __restrict__ wob) {
  const int b = blockIdx.x;
  const float* src;
  unsigned short* dst;
  int off;
  if (b < 16384) {
    src = x; dst = xb; off = b;
  } else if (b < 17408) {
    src = Wq; dst = wqkvb; off = b - 16384;
  } else if (b < 18432) {
    src = Wk; dst = wqkvb + 1048576; off = b - 17408;
  } else if (b < 19456) {
    src = Wv; dst = wqkvb + 2097152; off = b - 18432;
  } else {
    src = Wo; dst = wob; off = b - 19456;
  }
  const int i = (off * 256 + threadIdx.x) * 4;
  float4 f = *(const float4*)(src + i);
  ushort4 o;
  o.x = f2bf(f.x); o.y = f2bf(f.y); o.z = f2bf(f.z); o.w = f2bf(f.w);
  *(ushort4*)(dst + i) = o;
}

// ------- 256x256-tile 4-phase overlapped bf16 GEMM: C = A @ BT^T ---------
// R7/R8: R5's register footprint + stage placement + vmcnt ledger (PROVEN
// correct), but each phase is {reads; stages; MFMA; LGKM0; barrier} --
// ONE barrier per phase (4/K-tile, was 8), NO mid-phase drain, NO
// sched_barrier(0). RAW read->MFMA is compiler-tracked (ordinary ds_reads;
// hipcc emits fine-grained counted lgkmcnt), so the first MFMAs issue as
// soon as their fragments land and the remaining reads drain UNDER the
// MFMA cluster. R2/R5's mid-phase BARRIER+LGKM0 forced full serialization
// of the LDS pipe (~2300 cyc/K-tile/CU) against the MFMA pipe (~2050 cyc)
// == the measured 35% MfmaUtil plateau. R6's attempt at cross-phase reg
// pipelining spilled (FETCH+WRITE +196 MB of scratch traffic); this gets
// the overlap with zero extra registers.
//
// REGION READ MAP (waves at different (wm,wn) read different regions for
// the same LDA/LDB):
//   A-H0/A-H1: last read ph2 (LDA(1))   -> free after ph2's barrier
//   B-H0/B-H1: last read ph1 (LDB(1))   -> free after ph1's barrier
// Stage schedule (tile kt+2 into buf[cur]):
//   ph2: STAGE_B(kt+2,0/1)  (B free after ph1)
//   ph3: STAGE_A(kt+2,0/1)  (A free after ph2)
// WAR publication: LGKM0 before each phase-end barrier guarantees a wave's
// reads completed before it signals the barrier after which the region may
// be overwritten.
// vmcnt ledger (8 gloads/tile): prologue tile0 x8 -> VMCNT(0) hard
// boundary -> tile1 x8 in flight. At kt ph3, in flight = tile(kt+1) x8
// (issued during iter kt-1: full-iteration latency cover) + tile(kt+2) x8;
// VMCNT(8) drains tile kt+1 before iter kt+1 reads it, leaves kt+2 in
// flight. Tail: kt>=14 no stages; VMCNT(0).
//
// MODE 0: N=3072 (q|k|v), bias b0/b1/b2, ReLU on q,k; bf16 out.
// MODE 1: N=1024, bias b0, f32 out.
#define BARRIER()                           \
  do {                                      \
    asm volatile("" ::: "memory");          \
    __builtin_amdgcn_s_barrier();           \
    asm volatile("" ::: "memory");          \
  } while (0)
#define LGKM0 asm volatile("s_waitcnt lgkmcnt(0)" ::: "memory")
#define VMCNT(N) asm volatile("s_waitcnt vmcnt(" #N ")" ::: "memory")

template <int MODE>
__global__ __launch_bounds__(512, 2) void gemm256(
    const unsigned short* __restrict__ A,
    const unsigned short* __restrict__ BT,
    const float* __restrict__ b0, const float* __restrict__ b1,
    const float* __restrict__ b2,
    unsigned short* __restrict__ Oq, unsigned short* __restrict__ Ok,
    unsigned short* __restrict__ Ov, float* __restrict__ Of) {
  // 2 buffers x 4 regions (A-H0,A-H1,B-H0,B-H1) x 128rows x 64cols bf16.
  __shared__ __align__(16) unsigned short smem[65536];
  const int t = threadIdx.x;
  const int lane = t & 63, wid = t >> 6;
  const int wm = wid >> 2, wn = wid & 3;     // 2x4 wave grid, 128x64 out/wave
  const int mrow = lane & 15, quad = lane >> 4;

  int bid = blockIdx.x, bm, bn;
  if (MODE == 0) {  // 768 wgs: bijective XCD swizzle, A-panel-major chunks
    int s = (bid & 7) * 96 + (bid >> 3);
    bm = s / 12; bn = s - bm * 12;
  } else {          // 256 wgs
    int s = (bid & 7) * 32 + (bid >> 3);
    bm = s >> 2; bn = s & 3;
  }
  const int m0 = bm << 8;
  const int n0 = bn << 8;

  // Frag-read swizzle: chunkpos = wanted ^ (row&7); row&7 == mrow&7 since
  // all other row offsets are multiples of 8 (16,32,64,128-row strides).
  const int sw0 = ((quad ^ (mrow & 7)) << 3);
  const int sw1 = (((quad ^ 4) ^ (mrow & 7)) << 3);
  const int a_base = wm * 8192 + mrow * 64;
  const int b_base = 16384 + (wn >> 1) * 8192 + (((wn & 1) << 6) + mrow) * 64;
  // Staging: lane writes LDS chunkpos = lane&7 at region-row
  // srow = wid*8+(lane>>3); source col-chunk = chunkpos ^ (srow&7).
  const int s_dst0 = wid * 512 + lane * 8;
  const int srow = wid * 8 + (lane >> 3);
  const int csrc = ((lane & 7) ^ (lane >> 3)) << 3;
  const unsigned short* gAbase = A + (size_t)(m0 + srow) * 1024 + csrc;
  const unsigned short* gBbase = BT + (size_t)(n0 + srow) * 1024 + csrc;

#define STAGE_A(KT, H)                                              \
  do {                                                              \
    const unsigned short* _g = gAbase + ((H) << 17) + ((KT) << 6);  \
    const int _d = (((KT) & 1) << 15) + ((H) << 13) + s_dst0;       \
    gload16(_g, &smem[_d]);                                         \
    gload16(_g + 65536, &smem[_d + 4096]);                          \
  } while (0)
#define STAGE_B(KT, H)                                                     \
  do {                                                                     \
    const unsigned short* _g = gBbase + ((H) << 17) + ((KT) << 6);         \
    const int _d = (((KT) & 1) << 15) + 16384 + ((H) << 13) + s_dst0;      \
    gload16(_g, &smem[_d]);                                                \
    gload16(_g + 65536, &smem[_d + 4096]);                                 \
  } while (0)
#define LDA(MH)                                                  \
  do {                                                           \
    const int _ab = cb + a_base + ((MH) << 12);                  \
    _Pragma("unroll") for (int i = 0; i < 4; ++i) {              \
      aF[i][0] = *(const shortx8*)&smem[_ab + i * 1024 + sw0];   \
      aF[i][1] = *(const shortx8*)&smem[_ab + i * 1024 + sw1];   \
    }                                                            \
  } while (0)
#define LDB(NH)                                                      \
  do {                                                               \
    const int _bb = cb + b_base + ((NH) << 11);                      \
    _Pragma("unroll") for (int j = 0; j < 2; ++j) {                  \
      bF[NH][j][0] = *(const shortx8*)&smem[_bb + j * 1024 + sw0];   \
      bF[NH][j][1] = *(const shortx8*)&smem[_bb + j * 1024 + sw1];   \
    }                                                                \
  } while (0)
#define MFMAQ(MH, NH)                                                        \
  do {                                                                       \
    _Pragma("unroll") for (int ks = 0; ks < 2; ++ks)                         \
    _Pragma("unroll") for (int i = 0; i < 4; ++i)                            \
    _Pragma("unroll") for (int j = 0; j < 2; ++j)                            \
      acc[(MH) * 4 + i][(NH) * 2 + j] =                                      \
          __builtin_amdgcn_mfma_f32_16x16x32_bf16(                           \
              aF[i][ks], bF[NH][j][ks], acc[(MH) * 4 + i][(NH) * 2 + j], 0,  \
              0, 0);                                                         \
  } while (0)

  floatx4 acc[8][4] = {};
  shortx8 aF[4][2];
  shortx8 bF[2][2][2];

  // Prologue: tile 0 (8 gloads) -> HARD drain -> tile 1 (8 gloads).
  STAGE_A(0, 0); STAGE_A(0, 1); STAGE_B(0, 0); STAGE_B(0, 1);
  __builtin_amdgcn_sched_barrier(0);
  VMCNT(0);  // tile 0 fully resident (own share; barrier covers the rest)
  __builtin_amdgcn_sched_barrier(0);
  STAGE_A(1, 0); STAGE_A(1, 1); STAGE_B(1, 0); STAGE_B(1, 1);
  BARRIER();  // all waves' tile-0 shares resident; tile 1 x8 in flight

#pragma unroll 2
  for (int kt = 0; kt < 16; ++kt) {
    const int cb = (kt & 1) << 15;
    const bool pf = (kt < 14);
    // ---- ph0: read A-half(wm) rows 0-63 + B rows 0-63; MFMA (0,0).
    // Compiler's counted lgkmcnt overlaps read-drain with the MFMAs.
    LDA(0);
    LDB(0);
    __builtin_amdgcn_s_setprio(1);
    MFMAQ(0, 0);
    __builtin_amdgcn_s_setprio(0);
    LGKM0;   // publication drain (cheap: MFMAs already consumed the reads)
    BARRIER();
    // ---- ph1: read remaining B slices (last B reads); MFMA (0,1).
    LDB(1);
    __builtin_amdgcn_s_setprio(1);
    MFMAQ(0, 1);
    __builtin_amdgcn_s_setprio(0);
    LGKM0;
    BARRIER();
    // ---- ph2: read A second halves (last A reads); stage B(kt+2)
    //      (B regions free after ph1); MFMA (1,1).
    LDA(1);
    if (pf) { STAGE_B(kt + 2, 0); STAGE_B(kt + 2, 1); }
    __builtin_amdgcn_s_setprio(1);
    MFMAQ(1, 1);
    __builtin_amdgcn_s_setprio(0);
    LGKM0;
    BARRIER();
    // ---- ph3: stage A(kt+2) (A regions free after ph2); MFMA (1,0);
    //      boundary counted-vmcnt.
    if (pf) { STAGE_A(kt + 2, 0); STAGE_A(kt + 2, 1); }
    __builtin_amdgcn_s_setprio(1);
    MFMAQ(1, 0);
    __builtin_amdgcn_s_setprio(0);
    if (pf) {
      VMCNT(8);  // drain tile kt+1 (issued last iter); kt+2 stays in flight
    } else {
      VMCNT(0);  // tail drain (kt=14 drains tile 15; kt=15 no-op)
    }
    BARRIER();
  }

  // ---------------- epilogue ----------------
  if (MODE == 0) {
    const int sel = n0 >> 10;
    const float* bb = (sel == 0) ? b0 : ((sel == 1) ? b1 : b2);
    unsigned short* O = (sel == 0) ? Oq : ((sel == 1) ? Ok : Ov);
    const int nb = n0 & 1023;
    float bias[4];
#pragma unroll
    for (int j = 0; j < 4; ++j) bias[j] = bb[nb + wn * 64 + j * 16 + mrow];
    unsigned short* we = &smem[wid * 8192];  // per-wave 128x64 bf16, swizzled
#pragma unroll
    for (int mr = 0; mr < 8; ++mr)
#pragma unroll
      for (int j = 0; j < 4; ++j)
#pragma unroll
        for (int r = 0; r < 4; ++r) {
          const int row = mr * 16 + quad * 4 + r;
          const int col = j * 16 + mrow;
          float v = acc[mr][j][r] + bias[j];
          if (sel < 2) v = fmaxf(v, 0.0f);
          we[row * 64 + (((col >> 3) ^ (row & 7)) << 3) + (col & 7)] = f2bf(v);
        }
    __syncthreads();
#pragma unroll
    for (int it = 0; it < 16; ++it) {
      const int rr = it * 8 + (lane >> 3);
      const int cl = lane & 7;
      uint4 v = *(const uint4*)&we[rr * 64 + ((cl ^ (rr & 7)) << 3)];
      *(uint4*)&O[(size_t)(m0 + wm * 128 + rr) * 1024 + nb + wn * 64 + cl * 8] =
          v;
    }
  } else {
    float* wef = (float*)&smem[wid * 8192];  // per-wave 64x64 f32, swizzled
    float bias[4];
#pragma unroll
    for (int j = 0; j < 4; ++j) bias[j] = b0[n0 + wn * 64 + j * 16 + mrow];
#pragma unroll
    for (int h = 0; h < 2; ++h) {
#pragma unroll
      for (int i = 0; i < 4; ++i)
#pragma unroll
        for (int j = 0; j < 4; ++j)
#pragma unroll
          for (int r = 0; r < 4; ++r) {
            const int row = i * 16 + quad * 4 + r;
            const int col = j * 16 + mrow;
            wef[row * 64 + (((col >> 2) ^ (row & 7)) << 2) + (col & 3)] =
                acc[h * 4 + i][j][r] + bias[j];
          }
      __syncthreads();
#pragma unroll
      for (int it = 0; it < 16; ++it) {
        const int rr = it * 4 + (lane >> 4);
        const int cl = lane & 15;
        float4 v = *(const float4*)&wef[rr * 64 + ((cl ^ (rr & 7)) << 2)];
        *(float4*)&Of[(size_t)(m0 + wm * 128 + h * 64 + rr) * 1024 + n0 +
                      wn * 64 + cl * 4] = v;
      }
      __syncthreads();
    }
  }
#undef STAGE_A
#undef STAGE_B
#undef LDA
#undef LDB
#undef MFMAQ
}

// ---------------- fused retention (one axis, unchanged) ----------------
__global__ __launch_bounds__(256) void retention_fused(
    const unsigned short* __restrict__ S, const unsigned short* __restrict__ Kb,
    const unsigned short* __restrict__ Vb, unsigned short* __restrict__ D,
    int axis) {
  const int outer = blockIdx.x;
  const int n = blockIdx.y;
  __shared__ unsigned short lS[128 * 72];
  __shared__ unsigned short lKT[64 * 136];
  __shared__ unsigned short lVT[64 * 136];
  unsigned short* lKV = lVT;  // reused for kv^T [e][d] stride 72 after stage 1
  const int t = threadIdx.x;
  const size_t base = (axis == 0) ? ((size_t)outer << 17) : ((size_t)outer << 10);
  const size_t istr = (axis == 0) ? (size_t)1024 : (size_t)131072;
  const size_t nof = (size_t)(n << 6);

#pragma unroll
  for (int it = 0; it < 4; ++it) {
    const int r = it * 32 + (t >> 3);
    const int c = (t & 7) * 8;
    uint4 v = *(const uint4*)&S[base + (size_t)r * istr + nof + c];
    *(uint4*)&lS[r * 72 + c] = v;
  }
#pragma unroll
  for (int it = 0; it < 4; ++it) {
    const int w = it * 32 + (t & 31);
    const int d0 = (t >> 5) * 8;
    const size_t g = base + (size_t)w * istr + nof + d0;
    uint4 k4 = *(const uint4*)&Kb[g];
    uint4 v4 = *(const uint4*)&Vb[g];
    const unsigned short* kp = (const unsigned short*)&k4;
    const unsigned short* vp = (const unsigned short*)&v4;
#pragma unroll
    for (int i = 0; i < 8; ++i) {
      lKT[(d0 + i) * 136 + w] = kp[i];
      lVT[(d0 + i) * 136 + w] = vp[i];
    }
  }
  __syncthreads();

  const int lane = t & 63;
  const int wv = t >> 6;
  const int mrow = lane & 15;
  const int quad = lane >> 4;

  floatx4 acc1[4] = {};
#pragma unroll
  for (int ks = 0; ks < 4; ++ks) {
    shortx8 a = *(const shortx8*)&lVT[(wv * 16 + mrow) * 136 + ks * 32 + quad * 8];
#pragma unroll
    for (int j = 0; j < 4; ++j) {
      shortx8 b = *(const shortx8*)&lKT[(j * 16 + mrow) * 136 + ks * 32 + quad * 8];
      acc1[j] = __builtin_amdgcn_mfma_f32_16x16x32_bf16(a, b, acc1[j], 0, 0, 0);
    }
  }
  __syncthreads();  // all stage-1 reads of lVT done before aliasing as lKV
#pragma unroll
  for (int j = 0; j < 4; ++j)
#pragma unroll
    for (int r = 0; r < 4; ++r)
      lKV[(wv * 16 + quad * 4 + r) * 72 + j * 16 + mrow] = f2bf(acc1[j][r]);
  __syncthreads();

  floatx4 acc2[2][4] = {};
#pragma unroll
  for (int ks = 0; ks < 2; ++ks) {
    shortx8 a2[2], b2[4];
#pragma unroll
    for (int i = 0; i < 2; ++i)
      a2[i] = *(const shortx8*)&lS[(wv * 32 + i * 16 + mrow) * 72 + ks * 32 + quad * 8];
#pragma unroll
    for (int j = 0; j < 4; ++j)
      b2[j] = *(const shortx8*)&lKV[(j * 16 + mrow) * 72 + ks * 32 + quad * 8];
#pragma unroll
    for (int i = 0; i < 2; ++i)
#pragma unroll
      for (int j = 0; j < 4; ++j)
        acc2[i][j] = __builtin_amdgcn_mfma_f32_16x16x32_bf16(a2[i], b2[j],
                                                             acc2[i][j], 0, 0, 0);
  }
  __syncthreads();  // all stage-2 reads of lS done
#pragma unroll
  for (int i = 0; i < 2; ++i)
#pragma unroll
    for (int j = 0; j < 4; ++j)
#pragma unroll
      for (int r = 0; r < 4; ++r) {
        const int row = wv * 32 + i * 16 + quad * 4 + r;
        const int col = j * 16 + mrow;
        lS[row * 72 + col] = f2bf(acc2[i][j][r]);
      }
  __syncthreads();
#pragma unroll
  for (int it = 0; it < 4; ++it) {
    const int row = it * 32 + (t >> 3);
    const int c = (t & 7) * 8;
    uint4 v = *(const uint4*)&lS[row * 72 + c];
    *(uint4*)&D[base + (size_t)row * istr + nof + c] = v;
  }
}

extern "C" void kernel_launch(void* const* d_in, const int* in_sizes, int n_in,
                              void* d_out, int out_size, void* d_ws, size_t ws_size,
                              hipStream_t stream) {
  const float* x  = (const float*)d_in[0];
  const float* Wq = (const float*)d_in[1];
  const float* bq = (const float*)d_in[2];
  const float* Wk = (const float*)d_in[3];
  const float* bk = (const float*)d_in[4];
  const float* Wv = (const float*)d_in[5];
  const float* bv = (const float*)d_in[6];
  const float* Wo = (const float*)d_in[7];
  const float* bo = (const float*)d_in[8];
  float* out = (float*)d_out;

  char* ws = (char*)d_ws;
  unsigned short* xb    = (unsigned short*)(ws + 0);          // 16M elem
  unsigned short* wqkvb = (unsigned short*)(ws + 33554432);   // 3M elem
  unsigned short* wob   = (unsigned short*)(ws + 39845888);   // 1M elem
  unsigned short* qb    = (unsigned short*)(ws + 41943040);   // 16M elem
  unsigned short* kb    = (unsigned short*)(ws + 75497472);   // 16M elem
  unsigned short* vb    = (unsigned short*)(ws + 109051904);  // 16M elem
  unsigned short* out1  = xb;  // reuse: x not needed after projections
  unsigned short* out2  = qb;  // reuse: q not needed after axis-0 retention

  cvt_all<<<dim3(20480), dim3(256), 0, stream>>>(x, Wq, Wk, Wv, Wo, xb, wqkvb, wob);
  gemm256<0><<<dim3(768), dim3(512), 0, stream>>>(
      xb, wqkvb, bq, bk, bv, qb, kb, vb, (float*)nullptr);
  retention_fused<<<dim3(128, 16), dim3(256), 0, stream>>>(qb, kb, vb, out1, 0);
  retention_fused<<<dim3(128, 16), dim3(256), 0, stream>>>(out1, kb, vb, out2, 1);
  gemm256<1><<<dim3(256), dim3(512), 0, stream>>>(
      out2, wob, bo, nullptr, nullptr, nullptr, nullptr, nullptr, out);
}